// Round 7
// baseline (549.104 us; speedup 1.0000x reference)
//
#include <hip/hip_runtime.h>
#include <math.h>

// Problem constants
#define NB 2
#define NC 256
#define CG 16
#define HH 192
#define WW 192
#define HO 190
#define PP 144

// LDS: 7348 floats = 29392 B.
// Band area: up to 34 rows x 196 (row r at r*196: [0..3]=pads always zero,
//   [4..195]=data). Window reads at r*196 + 2+v2+dj: left spill -> own pads
//   [2,3], right spill -> next row's pads [0,1] (never written by staging).
// Epilogue: edge rows 0..11 (same layout), row 12 = permanent zero guard
//   (slots [0,1] catch edge-row-11 right spill), red[192][25] at 2548.
#define SMEM_FLOATS 7348

// ---------------------------------------------------------------------------
// Kernel 1: correlation-decomposed Gram. Same per-accumulator FMA order as
// rounds 1-6 -> bit-identical gram. THIS ROUND: 384-thread blocks, the two
// channel-pairs split across thread halves (threads 0-191: pair A cols 0-191,
// threads 192-383: pair B). Halves per-thread registers (mid[25] not
// mid[2][25], one prefetch ring) -> ~70 live VGPR -> ~24 waves/CU instead of
// the VGPR-capped ~15 (rounds 2-6 all sat at 26-31% VALUBusy = latency-bound
// at low occupancy). Same total FMA work; LDS band now feeds 6 waves.
// NO min-waves hint (caps poison regalloc: rounds 3,4,6).
// ---------------------------------------------------------------------------
__global__ __launch_bounds__(384) void gram_kernel(const float* __restrict__ x,
                                                   double* __restrict__ gram)
{
    __shared__ float smem[SMEM_FLOATS];
    float* const red_s = smem + 2548;

    const int v = threadIdx.x;                // 0..383
    const int half = (v >= 192);              // 0: pair A, 1: pair B
    const int v2 = half ? v - 192 : v;        // column 0..191

    // XCD-clustered decode: bid%8 = intended XCD; half-group hg (36 blocks)
    // pinned to XCD hg%8. Bijective over 2304 blocks.
    const int bid = blockIdx.x;
    const int vx = bid & 7;
    const int tq = bid >> 3;                  // 0..287
    const int idxw = tq / 36;                 // 0..7
    const int rr0 = tq - idxw * 36;           // 0..35
    const int hg = idxw * 8 + vx;             // 0..63
    const int bg = hg >> 1;
    int r = rr0 + 36 * (hg & 1);              // 0..71
    int c2 = 0;
    while (r >= (c2 + 2) / 2) { r -= (c2 + 2) / 2; ++c2; }
    const int c1a = 2 * r;
    int c1b = 2 * r + 1;
    const bool bval = (c1b <= c2);
    if (!bval) c1b = c2;
    const int b = bg >> 4, g = bg & 15;

    const float* __restrict__ x2g = x + ((size_t)(b * NC + g * CG + c2)) * (HH * WW);
    // this thread's own channel (pair A -> c1a, pair B -> c1b)
    const float* __restrict__ xcm =
        x + ((size_t)(b * NC + g * CG + (half ? c1b : c1a))) * (HH * WW);

    // zero pad slots [0..3] of rows 0..36 once; staging never writes pads.
    if (v < 148) smem[(v >> 2) * 196 + (v & 3)] = 0.f;

    float mid[25];
#pragma unroll
    for (int o = 0; o < 25; ++o) mid[o] = 0.f;

    float win[5][5];
    float ca[5];
#pragma unroll
    for (int k = 0; k < 5; ++k)               // ring: ca[(u-2)%5] holds row u
        ca[k] = xcm[(size_t)(2 + k) * WW + v2];

// One u-step. P = phase (compile-time), lbase = in-band step base (runtime,
// multiple of 5), ubase = u0 + lbase. u = ubase + P; staged row lbase+P+4 is
// the new window row (slot (P+4)%5); refill ca[P] with row u+5.
#define USTEP(P, PF)                                                          \
    {                                                                         \
        _Pragma("unroll")                                                     \
        for (int dj = 0; dj < 5; ++dj)                                        \
            win[((P) + 4) % 5][dj] = smem[(lbase + (P) + 4) * 196 + 2 + v2 + dj]; \
        const float a1 = ca[(P)];                                             \
        if (PF) ca[(P)] = xcm[(size_t)(ubase + (P) + 5) * WW + v2];           \
        _Pragma("unroll")                                                     \
        for (int kk = 0; kk < 5; ++kk) {                                      \
            _Pragma("unroll")                                                 \
            for (int dj = 0; dj < 5; ++dj) {                                  \
                const float xv = win[((P) + kk) % 5][dj];                     \
                mid[kk * 5 + dj] = fmaf(a1, xv, mid[kk * 5 + dj]);            \
            }                                                                 \
        }                                                                     \
    }

    // 7 bands: 6 x 30 steps (u=2..181, 34 staged rows) + tail 8 steps
    // (u=182..189, 12 staged rows). u continuous; ring phase (u-2)%5.
    for (int band = 0; band < 7; ++band) {
        const bool full = (band < 6);
        const int u0 = 2 + band * 30;
        const int row0 = u0 - 2;
        const int limit = (full ? 34 : 12) * 48;   // float4 slots
        __syncthreads();
        for (int it = 0; it < (full ? 5 : 2); ++it) {
            const int idx = it * 384 + v;
            if (idx < limit) {
                const int rr2 = idx / 48;
                const int c4 = (idx - rr2 * 48) * 4;
                const float4 val = *(const float4*)(x2g + (size_t)(row0 + rr2) * WW + c4);
                *(float4*)(&smem[rr2 * 196 + 4 + c4]) = val;
            }
        }
        __syncthreads();
        // prologue: staged rows 0..3 -> win slots 0..3
#pragma unroll
        for (int k = 0; k < 4; ++k)
#pragma unroll
        for (int dj = 0; dj < 5; ++dj)
            win[k][dj] = smem[k * 196 + 2 + v2 + dj];

        if (full) {
            for (int it = 0; it < 6; ++it) {       // rolled: small hot body
                const int lbase = it * 5;
                const int ubase = u0 + lbase;
                USTEP(0, 1) USTEP(1, 1) USTEP(2, 1) USTEP(3, 1) USTEP(4, 1)
            }
        } else {
            {   // steps 0..4 (u=182..186), refills target rows 187..191
                const int lbase = 0;
                const int ubase = u0;
                USTEP(0, 1) USTEP(1, 1) USTEP(2, 1) USTEP(3, 1) USTEP(4, 1)
            }
            {   // steps 5..7 (u=187..189), no refill
                const int lbase = 5;
                const int ubase = u0 + 5;
                USTEP(0, 0) USTEP(1, 0) USTEP(2, 0)
            }
        }
    }
#undef USTEP

    // stage edge buffer: buf i<6 -> abs row i-2 (OOB zero), i>=6 -> 188+(i-6).
    // Row 12 = zero guard (pads catch edge-row-11 right spill); red_s at 2548.
    __syncthreads();
#pragma unroll
    for (int ii = 0; ii < 6; ++ii) {
        const int i = ii * 2 + half;          // halves cover even/odd rows
        const int ar = (i < 6) ? (i - 2) : (188 + i - 6);
        const float val = (ar >= 0 && ar <= 191) ? x2g[(size_t)ar * WW + v2] : 0.f;
        smem[i * 196 + 4 + v2] = val;
    }
    __syncthreads();

    double* const gp = gram + (size_t)bg * (PP * PP);

#pragma unroll
    for (int i1 = 0; i1 < 3; ++i1) {
        const int ra = (i1 == 0) ? 0 : ((i1 == 1) ? 1 : 190);
        const int rb = (i1 == 0) ? 1 : ((i1 == 1) ? 190 : 191);
#pragma unroll
        for (int c = 0; c < 2; ++c) {
            // the half that owns this pair writes its corrected windows
            if ((c == 0) ? (v < 192) : (v >= 192)) {
                const float xra = xcm[(size_t)ra * WW + v2];
                const float xrb = xcm[(size_t)rb * WW + v2];
#pragma unroll
                for (int k = 0; k < 5; ++k) {
                    const int bufa = (ra < 2) ? (ra + k) : (ra + k - 184);
                    const int bufb = (rb < 2) ? (rb + k) : (rb + k - 184);
#pragma unroll
                    for (int dj = 0; dj < 5; ++dj) {
                        float cw = mid[k * 5 + dj];
                        cw = fmaf(xra, smem[bufa * 196 + 2 + v2 + dj], cw);
                        cw = fmaf(xrb, smem[bufb * 196 + 2 + v2 + dj], cw);
                        red_s[v2 * 25 + k * 5 + dj] = cw;
                    }
                }
            }
            __syncthreads();
            float e0 = 0.f, e1 = 0.f, e190 = 0.f, e191 = 0.f;
            if (v < 25) {
                e0   = red_s[0 * 25 + v];
                e1   = red_s[1 * 25 + v];
                e190 = red_s[190 * 25 + v];
                e191 = red_s[191 * 25 + v];
            }
            __syncthreads();
            // tree reduce over columns: 192 -> 96 -> ... -> 3 (stride 25: conflict-free)
#pragma unroll
            for (int s = 96; s >= 3; s >>= 1) {
                for (int idx = v; idx < s * 25; idx += 384) {
                    const int vv = idx / 25, o = idx - vv * 25;
                    red_s[vv * 25 + o] += red_s[(vv + s) * 25 + o];
                }
                __syncthreads();
            }
            if (v < 25 && (c == 0 || bval)) {
                const int di = v / 5 - 2, dj = v - (v / 5) * 5 - 2;
                const int i2 = i1 + di;
                if (i2 >= 0 && i2 <= 2) {
                    const float S = red_s[0 * 25 + v] + red_s[1 * 25 + v] + red_s[2 * 25 + v];
                    const int c1 = (c == 0) ? c1a : c1b;
#pragma unroll
                    for (int j1 = 0; j1 < 3; ++j1) {
                        const int j2 = j1 + dj;
                        if (j2 < 0 || j2 > 2) continue;
                        const float W = S - ((j1 == 0) ? (e190 + e191)
                                          : (j1 == 1) ? (e0 + e191)
                                                      : (e0 + e1));
                        const int p = c1 * 9 + i1 * 3 + j1;
                        const int q = c2 * 9 + i2 * 3 + j2;
                        gp[p * PP + q] = (double)W;
                        if (c1 != c2) gp[q * PP + p] = (double)W;
                    }
                }
            }
            __syncthreads();   // red reused by next (i1,c)
        }
    }
}

// ---------------------------------------------------------------------------
// Kernel 2: per-group argmin (f64 d2, first-min tiebreak), bincount over both
// batches, stable top-3 (smallest index on count ties, matching lax.top_k).
// ---------------------------------------------------------------------------
__global__ __launch_bounds__(320) void topk_kernel(const double* __restrict__ gram,
                                                   float* __restrict__ pf,
                                                   int* __restrict__ pi)
{
    const int g = blockIdx.x;
    __shared__ double sdiag[2][PP];
    __shared__ int counts[PP];
    const int tid = threadIdx.x;
    if (tid < PP) counts[tid] = 0;
    if (tid < 2 * PP) {
        const int b = tid / PP, p = tid % PP;
        const double* gb = gram + (size_t)(b * 16 + g) * (PP * PP);
        sdiag[b][p] = gb[p * PP + p];
    }
    __syncthreads();
    if (tid < 2 * PP) {
        const int b = tid / PP, p = tid % PP;
        const double* row = gram + ((size_t)(b * 16 + g) * PP + p) * PP;
        const double sp = sdiag[b][p];
        double best = 1e300;
        int bi = 0;
        for (int q = 0; q < PP; ++q) {
            if (q == p) continue;
            const double d2 = sp + sdiag[b][q] - 2.0 * row[q];
            if (d2 < best) { best = d2; bi = q; }   // strict < : first occurrence
        }
        atomicAdd(&counts[bi], 1);
    }
    __syncthreads();
    if (tid == 0) {
        int sel[3], cv[3];
        for (int o = 0; o < 3; ++o) {
            int bc = -1, bp = 0;
            for (int p = 0; p < PP; ++p) {
                bool taken = false;
                for (int u = 0; u < o; ++u) if (sel[u] == p) taken = true;
                if (!taken && counts[p] > bc) { bc = counts[p]; bp = p; } // > keeps lowest idx
            }
            sel[o] = bp; cv[o] = bc;
        }
        const int tot = cv[0] + cv[1] + cv[2];
        for (int o = 0; o < 3; ++o) {
            pf[g * 4 + o] = (float)cv[o];
            pi[g * 4 + o] = sel[o];
        }
        pf[g * 4 + 3] = (float)tot;
    }
}

// ---------------------------------------------------------------------------
// Kernel 3: fused scale->floor->fold stencil. t1,t2 are plain f32 muls
// (== __fmul_rn == reference). Division via f64 reciprocal-multiply:
// bit-exact (total<=288 => exact quotients >=2^-34 rel from any f32 rounding
// midpoint, exact ties impossible, f64 error <=2^-52 -> identical rounding).
// Interior and edge in separate kernels (no divergent waves).
// ---------------------------------------------------------------------------
template <bool EDGE>
__device__ __forceinline__ void motif_quad(const float* __restrict__ x,
                                           const float* __restrict__ pf,
                                           const int* __restrict__ pi,
                                           float* __restrict__ out,
                                           int b, int ch, int h, int w0)
{
    const int g = ch >> 4;
    const size_t base = ((size_t)(b * NC + ch)) * (HH * WW);
    const float4 xv4 = *(const float4*)(x + base + (size_t)h * WW + w0);
    const float xs[4] = {xv4.x, xv4.y, xv4.z, xv4.w};
    float acc[4] = {0.f, 0.f, 0.f, 0.f};
    const float total = pf[g * 4 + 3];
    const double invd = 1.0 / (double)total;

#pragma unroll
    for (int o = 0; o < 3; ++o) {
        const int p = pi[g * 4 + o];
        const float cff = pf[g * 4 + o];
        const int co = p / 9;
        const int kk = p - co * 9;
        const int io = kk / 3, jo = kk - (kk / 3) * 3;
        const float* Rb = x + ((size_t)(b * NC + g * CG + co)) * (HH * WW);
#pragma unroll
        for (int i = 0; i < 3; ++i) {
            const int ho = h - i;
            bool rowok = true;
            int hr = ho + io;
            if (EDGE) {
                rowok = (ho >= 0) && (ho < HO);
                hr = hr < 0 ? 0 : (hr > HH - 1 ? HH - 1 : hr);
            }
            const float* row = Rb + (size_t)hr * WW;
            float rv[6];
#pragma unroll
            for (int u = 0; u < 6; ++u) {
                int col = w0 - 2 + jo + u;
                if (EDGE) col = col < 0 ? 0 : (col > WW - 1 ? WW - 1 : col);
                rv[u] = row[col];
            }
#pragma unroll
            for (int j = 0; j < 3; ++j)
#pragma unroll
            for (int q = 0; q < 4; ++q) {
                const float r2 = rv[q - j + 2];
                const float t1 = xs[q] * r2;                  // == __fmul_rn
                const float t2 = t1 * cff;                    // == __fmul_rn
                const float qf = (float)((double)t2 * invd);  // == __fdiv_rn(t2,total)
                const float vfl = floorf(qf);
                if (EDGE) {
                    const int wo = w0 + q - j;
                    const bool ok = rowok && (wo >= 0) && (wo < HO);
                    acc[q] += ok ? vfl : 0.f;
                } else {
                    acc[q] += vfl;
                }
            }
        }
    }
    float4 ov = make_float4(acc[0], acc[1], acc[2], acc[3]);
    *(float4*)(out + base + (size_t)h * WW + w0) = ov;
}

// interior: h in [2,189], w4 in [1,46] -> no clamps/masks anywhere.
__global__ __launch_bounds__(256) void out_interior(const float* __restrict__ x,
                                                    const float* __restrict__ pf,
                                                    const int* __restrict__ pi,
                                                    float* __restrict__ out)
{
    const int gid = blockIdx.x * 256 + threadIdx.x;
    const int w4i = gid % 46;
    int t = gid / 46;
    const int h = 2 + t % 188; t /= 188;
    const int ch = t & 255;
    const int b = t >> 8;
    motif_quad<false>(x, pf, pi, out, b, ch, h, (w4i + 1) * 4);
}

// edge: 568 quads per (b,ch): h in {0,1,190,191} x all 48 w4, plus
// h in [2,189] x w4 in {0,47}.
__global__ __launch_bounds__(256) void out_edge(const float* __restrict__ x,
                                                const float* __restrict__ pf,
                                                const int* __restrict__ pi,
                                                float* __restrict__ out)
{
    const int gid = blockIdx.x * 256 + threadIdx.x;
    const int e = gid % 568;
    int t = gid / 568;
    const int ch = t & 255;
    const int b = t >> 8;
    int h, w4;
    if (e < 192) {
        const int hs = e / 48;
        h = (hs < 2) ? hs : 188 + hs;         // 0,1,190,191
        w4 = e % 48;
    } else {
        const int e2 = e - 192;
        h = 2 + (e2 >> 1);
        w4 = (e2 & 1) ? 47 : 0;
    }
    motif_quad<true>(x, pf, pi, out, b, ch, h, w4 * 4);
}

// ---------------------------------------------------------------------------
extern "C" void kernel_launch(void* const* d_in, const int* in_sizes, int n_in,
                              void* d_out, int out_size, void* d_ws, size_t ws_size,
                              hipStream_t stream)
{
    const float* x = (const float*)d_in[0];
    float* out = (float*)d_out;

    double* gram = (double*)d_ws;
    const size_t gram_bytes = (size_t)32 * PP * PP * sizeof(double); // 5,308,416 B
    float* pf = (float*)((char*)d_ws + gram_bytes);
    int* pi = (int*)((char*)d_ws + gram_bytes + 256);

    gram_kernel<<<2304, 384, 0, stream>>>(x, gram);
    topk_kernel<<<16, 320, 0, stream>>>(gram, pf, pi);
    out_interior<<<17296, 256, 0, stream>>>(x, pf, pi, out);  // 2*256*188*46/256
    out_edge<<<1136, 256, 0, stream>>>(x, pf, pi, out);       // 2*256*568/256
}

// Round 8
// 427.775 us; speedup vs baseline: 1.2836x; 1.2836x over previous
//
#include <hip/hip_runtime.h>
#include <math.h>

// Problem constants
#define NB 2
#define NC 256
#define CG 16
#define HH 192
#define WW 192
#define HO 190
#define PP 144

// LDS: 7348 floats = 29392 B -> 5 blocks/CU (with VGPR<=128: 15 waves/CU).
// Band area: 35 rows x 196 (row r at r*196: [0..3]=pads always zero,
//   [4..195]=data). Window reads at r*196 + 2+v+dj: left spill -> own pads
//   [2,3], right spill -> next row's pads [0,1] (never written by staging).
// Epilogue: edge rows 0..11 (same layout), row 12 = permanent zero guard
//   (slots [0,1] catch edge-row-11 right spill), red[192][25] at 2548.
#define SMEM_FLOATS 7348

// ---------------------------------------------------------------------------
// Kernel 1: correlation-decomposed Gram. Same per-accumulator FMA order and
// operand values as rounds 1-7 -> bit-identical gram.
// THIS ROUND (on top of round-6 winner: 192 thr, (192,2), rolled body, XCD
// swizzle): 1-STEP SOFTWARE-PIPELINED WINDOW RING (win[6][5]): at step u we
// load row u+3; all 25 FMAs of step u consume rows loaded >=1 step earlier,
// so the ds_read->FMA same-step dependency (the ~120cyc exposed LDS latency
// behind the 30% VALUBusy plateau of rounds 2/5/6) is gone. Staging 35 rows
// per band makes step-29's prefetch double as the next band's prologue
// (bands chain; only band 0 has a 5-row prologue). Global ca/cb ring
// deepened to 6 and carried across bands.
// ---------------------------------------------------------------------------
__global__ __launch_bounds__(192, 2) void gram_kernel(const float* __restrict__ x,
                                                      double* __restrict__ gram)
{
    __shared__ float smem[SMEM_FLOATS];
    float* const red_s = smem + 2548;

    const int v = threadIdx.x;                // column 0..191
    const int vr = v / 48;                    // staging row sub-index
    const int vc4 = (v - vr * 48) * 4;        // staging col (floats)

    // XCD-clustered decode: bid%8 = intended XCD; half-group hg (36 blocks)
    // pinned to XCD hg%8. Bijective over 2304 blocks.
    const int bid = blockIdx.x;
    const int vx = bid & 7;
    const int tq = bid >> 3;                  // 0..287
    const int idxw = tq / 36;                 // 0..7
    const int rr0 = tq - idxw * 36;           // 0..35
    const int hg = idxw * 8 + vx;             // 0..63
    const int bg = hg >> 1;
    int r = rr0 + 36 * (hg & 1);              // 0..71
    int c2 = 0;
    while (r >= (c2 + 2) / 2) { r -= (c2 + 2) / 2; ++c2; }
    const int c1a = 2 * r;
    int c1b = 2 * r + 1;
    const bool bval = (c1b <= c2);
    if (!bval) c1b = c2;
    const int b = bg >> 4, g = bg & 15;

    const float* __restrict__ xa  = x + ((size_t)(b * NC + g * CG + c1a)) * (HH * WW);
    const float* __restrict__ xb  = x + ((size_t)(b * NC + g * CG + c1b)) * (HH * WW);
    const float* __restrict__ x2g = x + ((size_t)(b * NC + g * CG + c2 )) * (HH * WW);

    // zero pad slots [0..3] of rows 0..36 once; staging never writes pads.
    if (v < 148) smem[(v >> 2) * 196 + (v & 3)] = 0.f;

    float mid[2][25];
#pragma unroll
    for (int o = 0; o < 25; ++o) { mid[0][o] = 0.f; mid[1][o] = 0.f; }

    float win[6][5];                          // slot s holds row local L, L%6==s
    float ca[6], cb[6];                       // ca[(u-2)%6] holds xa row u
#pragma unroll
    for (int k = 0; k < 6; ++k) {             // rows 2..7
        ca[k] = xa[(size_t)(2 + k) * WW + v];
        cb[k] = xb[(size_t)(2 + k) * WW + v];
    }

// One u-step. P = phase = LS%6 (compile-time), LS = lbase+P local step,
// u = ubase+P. Consumes ca[P]/cb[P] (row u) and win slots (P+kk)%6 (rows
// local LS..LS+4, all loaded at least one step earlier). Prefetches:
//   WPF: window row local LS+5 -> slot (P+5)%6 (not used this step);
//   GPF: ca[P]/cb[P] <- row u+6 (consumed 6 steps later).
#define USTEP6(P, WPF, GPF)                                                   \
    {                                                                         \
        const float a1 = ca[(P)];                                             \
        const float b1 = cb[(P)];                                             \
        if (GPF) {                                                            \
            ca[(P)] = xa[(size_t)(ubase + (P) + 6) * WW + v];                 \
            cb[(P)] = xb[(size_t)(ubase + (P) + 6) * WW + v];                 \
        }                                                                     \
        if (WPF) {                                                            \
            _Pragma("unroll")                                                 \
            for (int dj = 0; dj < 5; ++dj)                                    \
                win[((P) + 5) % 6][dj] = smem[(lbase + (P) + 5) * 196 + 2 + v + dj]; \
        }                                                                     \
        _Pragma("unroll")                                                     \
        for (int kk = 0; kk < 5; ++kk) {                                      \
            _Pragma("unroll")                                                 \
            for (int dj = 0; dj < 5; ++dj) {                                  \
                const float xv = win[((P) + kk) % 6][dj];                     \
                mid[0][kk * 5 + dj] = fmaf(a1, xv, mid[0][kk * 5 + dj]);      \
                mid[1][kk * 5 + dj] = fmaf(b1, xv, mid[1][kk * 5 + dj]);      \
            }                                                                 \
        }                                                                     \
    }

    // 7 bands: 6 x 30 steps (u=2..181, stage 35 rows: local 0..34) + tail
    // 8 steps (u=182..189, stage 12 rows: local 0..11 = abs 180..191).
    // Step LS prefetches window row local LS+5; LS=29 loads local 34 which
    // IS next band's local 4 (same abs row) -> no prologue after band 0.
    for (int band = 0; band < 7; ++band) {
        const bool full = (band < 6);
        const int u0 = 2 + band * 30;
        const int row0 = u0 - 2;
        const int limit = (full ? 35 : 12) * 48;   // float4 slots
        __syncthreads();
        for (int it = 0; it < (full ? 9 : 3); ++it) {
            const int idx = it * 192 + v;
            if (idx < limit) {
                const int rr2 = idx / 48;
                const int c4 = (idx - rr2 * 48) * 4;
                const float4 val = *(const float4*)(x2g + (size_t)(row0 + rr2) * WW + c4);
                *(float4*)(&smem[rr2 * 196 + 4 + c4]) = val;
            }
        }
        __syncthreads();
        if (band == 0) {
            // only prologue of the whole kernel: locals 0..4 -> slots 0..4
#pragma unroll
            for (int k = 0; k < 5; ++k)
#pragma unroll
            for (int dj = 0; dj < 5; ++dj)
                win[k][dj] = smem[k * 196 + 2 + v + dj];
        }

        if (full) {
            for (int it = 0; it < 5; ++it) {       // rolled: small hot body
                const int lbase = it * 6;
                const int ubase = u0 + lbase;
                USTEP6(0, 1, 1) USTEP6(1, 1, 1) USTEP6(2, 1, 1)
                USTEP6(3, 1, 1) USTEP6(4, 1, 1) USTEP6(5, 1, 1)
            }
        } else {
            {   // steps 0..5 (u=182..187); GPF only LS<=1 (rows 188,189)
                const int lbase = 0;
                const int ubase = u0;
                USTEP6(0, 1, 1) USTEP6(1, 1, 1) USTEP6(2, 1, 0)
                USTEP6(3, 1, 0) USTEP6(4, 1, 0) USTEP6(5, 1, 0)
            }
            {   // steps 6,7 (u=188,189); WPF for LS=6 (local 11), none LS=7
                const int lbase = 6;
                const int ubase = u0 + 6;
                USTEP6(0, 1, 0) USTEP6(1, 0, 0)
            }
        }
    }
#undef USTEP6

    // stage edge buffer: buf i<6 -> abs row i-2 (OOB zero), i>=6 -> 188+(i-6).
    // Row 12 = zero guard (pads catch edge-row-11 right spill); red_s at 2548.
    __syncthreads();
    for (int i = 0; i < 12; ++i) {
        const int ar = (i < 6) ? (i - 2) : (188 + i - 6);
        const float val = (ar >= 0 && ar <= 191) ? x2g[(size_t)ar * WW + v] : 0.f;
        smem[i * 196 + 4 + v] = val;
    }
    __syncthreads();

    double* const gp = gram + (size_t)bg * (PP * PP);

#pragma unroll
    for (int i1 = 0; i1 < 3; ++i1) {
        const int ra = (i1 == 0) ? 0 : ((i1 == 1) ? 1 : 190);
        const int rb = (i1 == 0) ? 1 : ((i1 == 1) ? 190 : 191);
#pragma unroll
        for (int c = 0; c < 2; ++c) {
            const float* __restrict__ xc = (c == 0) ? xa : xb;
            const float xra = xc[(size_t)ra * WW + v];
            const float xrb = xc[(size_t)rb * WW + v];
#pragma unroll
            for (int k = 0; k < 5; ++k) {
                const int bufa = (ra < 2) ? (ra + k) : (ra + k - 184);
                const int bufb = (rb < 2) ? (rb + k) : (rb + k - 184);
#pragma unroll
                for (int dj = 0; dj < 5; ++dj) {
                    float cw = mid[c][k * 5 + dj];
                    cw = fmaf(xra, smem[bufa * 196 + 2 + v + dj], cw);
                    cw = fmaf(xrb, smem[bufb * 196 + 2 + v + dj], cw);
                    red_s[v * 25 + k * 5 + dj] = cw;
                }
            }
            __syncthreads();
            float e0 = 0.f, e1 = 0.f, e190 = 0.f, e191 = 0.f;
            if (v < 25) {
                e0   = red_s[0 * 25 + v];
                e1   = red_s[1 * 25 + v];
                e190 = red_s[190 * 25 + v];
                e191 = red_s[191 * 25 + v];
            }
            __syncthreads();
            // tree reduce over columns: 192 -> 96 -> ... -> 3 (stride 25: conflict-free)
#pragma unroll
            for (int s = 96; s >= 3; s >>= 1) {
                for (int idx = v; idx < s * 25; idx += 192) {
                    const int vv = idx / 25, o = idx - vv * 25;
                    red_s[vv * 25 + o] += red_s[(vv + s) * 25 + o];
                }
                __syncthreads();
            }
            if (v < 25 && (c == 0 || bval)) {
                const int di = v / 5 - 2, dj = v - (v / 5) * 5 - 2;
                const int i2 = i1 + di;
                if (i2 >= 0 && i2 <= 2) {
                    const float S = red_s[0 * 25 + v] + red_s[1 * 25 + v] + red_s[2 * 25 + v];
                    const int c1 = (c == 0) ? c1a : c1b;
#pragma unroll
                    for (int j1 = 0; j1 < 3; ++j1) {
                        const int j2 = j1 + dj;
                        if (j2 < 0 || j2 > 2) continue;
                        const float W = S - ((j1 == 0) ? (e190 + e191)
                                          : (j1 == 1) ? (e0 + e191)
                                                      : (e0 + e1));
                        const int p = c1 * 9 + i1 * 3 + j1;
                        const int q = c2 * 9 + i2 * 3 + j2;
                        gp[p * PP + q] = (double)W;
                        if (c1 != c2) gp[q * PP + p] = (double)W;
                    }
                }
            }
            __syncthreads();   // red reused by next (i1,c)
        }
    }
}

// ---------------------------------------------------------------------------
// Kernel 2: per-group argmin (f64 d2, first-min tiebreak), bincount over both
// batches, stable top-3 (smallest index on count ties, matching lax.top_k).
// ---------------------------------------------------------------------------
__global__ __launch_bounds__(320) void topk_kernel(const double* __restrict__ gram,
                                                   float* __restrict__ pf,
                                                   int* __restrict__ pi)
{
    const int g = blockIdx.x;
    __shared__ double sdiag[2][PP];
    __shared__ int counts[PP];
    const int tid = threadIdx.x;
    if (tid < PP) counts[tid] = 0;
    if (tid < 2 * PP) {
        const int b = tid / PP, p = tid % PP;
        const double* gb = gram + (size_t)(b * 16 + g) * (PP * PP);
        sdiag[b][p] = gb[p * PP + p];
    }
    __syncthreads();
    if (tid < 2 * PP) {
        const int b = tid / PP, p = tid % PP;
        const double* row = gram + ((size_t)(b * 16 + g) * PP + p) * PP;
        const double sp = sdiag[b][p];
        double best = 1e300;
        int bi = 0;
        for (int q = 0; q < PP; ++q) {
            if (q == p) continue;
            const double d2 = sp + sdiag[b][q] - 2.0 * row[q];
            if (d2 < best) { best = d2; bi = q; }   // strict < : first occurrence
        }
        atomicAdd(&counts[bi], 1);
    }
    __syncthreads();
    if (tid == 0) {
        int sel[3], cv[3];
        for (int o = 0; o < 3; ++o) {
            int bc = -1, bp = 0;
            for (int p = 0; p < PP; ++p) {
                bool taken = false;
                for (int u = 0; u < o; ++u) if (sel[u] == p) taken = true;
                if (!taken && counts[p] > bc) { bc = counts[p]; bp = p; } // > keeps lowest idx
            }
            sel[o] = bp; cv[o] = bc;
        }
        const int tot = cv[0] + cv[1] + cv[2];
        for (int o = 0; o < 3; ++o) {
            pf[g * 4 + o] = (float)cv[o];
            pi[g * 4 + o] = sel[o];
        }
        pf[g * 4 + 3] = (float)tot;
    }
}

// ---------------------------------------------------------------------------
// Kernel 3: fused scale->floor->fold stencil. t1,t2 are plain f32 muls
// (== __fmul_rn == reference). Division via f64 reciprocal-multiply:
// bit-exact (total<=288 => exact quotients >=2^-34 rel from any f32 rounding
// midpoint, exact ties impossible, f64 error <=2^-52 -> identical rounding).
// Interior and edge in separate kernels (no divergent waves).
// ---------------------------------------------------------------------------
template <bool EDGE>
__device__ __forceinline__ void motif_quad(const float* __restrict__ x,
                                           const float* __restrict__ pf,
                                           const int* __restrict__ pi,
                                           float* __restrict__ out,
                                           int b, int ch, int h, int w0)
{
    const int g = ch >> 4;
    const size_t base = ((size_t)(b * NC + ch)) * (HH * WW);
    const float4 xv4 = *(const float4*)(x + base + (size_t)h * WW + w0);
    const float xs[4] = {xv4.x, xv4.y, xv4.z, xv4.w};
    float acc[4] = {0.f, 0.f, 0.f, 0.f};
    const float total = pf[g * 4 + 3];
    const double invd = 1.0 / (double)total;

#pragma unroll
    for (int o = 0; o < 3; ++o) {
        const int p = pi[g * 4 + o];
        const float cff = pf[g * 4 + o];
        const int co = p / 9;
        const int kk = p - co * 9;
        const int io = kk / 3, jo = kk - (kk / 3) * 3;
        const float* Rb = x + ((size_t)(b * NC + g * CG + co)) * (HH * WW);
#pragma unroll
        for (int i = 0; i < 3; ++i) {
            const int ho = h - i;
            bool rowok = true;
            int hr = ho + io;
            if (EDGE) {
                rowok = (ho >= 0) && (ho < HO);
                hr = hr < 0 ? 0 : (hr > HH - 1 ? HH - 1 : hr);
            }
            const float* row = Rb + (size_t)hr * WW;
            float rv[6];
#pragma unroll
            for (int u = 0; u < 6; ++u) {
                int col = w0 - 2 + jo + u;
                if (EDGE) col = col < 0 ? 0 : (col > WW - 1 ? WW - 1 : col);
                rv[u] = row[col];
            }
#pragma unroll
            for (int j = 0; j < 3; ++j)
#pragma unroll
            for (int q = 0; q < 4; ++q) {
                const float r2 = rv[q - j + 2];
                const float t1 = xs[q] * r2;                  // == __fmul_rn
                const float t2 = t1 * cff;                    // == __fmul_rn
                const float qf = (float)((double)t2 * invd);  // == __fdiv_rn(t2,total)
                const float vfl = floorf(qf);
                if (EDGE) {
                    const int wo = w0 + q - j;
                    const bool ok = rowok && (wo >= 0) && (wo < HO);
                    acc[q] += ok ? vfl : 0.f;
                } else {
                    acc[q] += vfl;
                }
            }
        }
    }
    float4 ov = make_float4(acc[0], acc[1], acc[2], acc[3]);
    *(float4*)(out + base + (size_t)h * WW + w0) = ov;
}

// interior: h in [2,189], w4 in [1,46] -> no clamps/masks anywhere.
__global__ __launch_bounds__(256) void out_interior(const float* __restrict__ x,
                                                    const float* __restrict__ pf,
                                                    const int* __restrict__ pi,
                                                    float* __restrict__ out)
{
    const int gid = blockIdx.x * 256 + threadIdx.x;
    const int w4i = gid % 46;
    int t = gid / 46;
    const int h = 2 + t % 188; t /= 188;
    const int ch = t & 255;
    const int b = t >> 8;
    motif_quad<false>(x, pf, pi, out, b, ch, h, (w4i + 1) * 4);
}

// edge: 568 quads per (b,ch): h in {0,1,190,191} x all 48 w4, plus
// h in [2,189] x w4 in {0,47}.
__global__ __launch_bounds__(256) void out_edge(const float* __restrict__ x,
                                                const float* __restrict__ pf,
                                                const int* __restrict__ pi,
                                                float* __restrict__ out)
{
    const int gid = blockIdx.x * 256 + threadIdx.x;
    const int e = gid % 568;
    int t = gid / 568;
    const int ch = t & 255;
    const int b = t >> 8;
    int h, w4;
    if (e < 192) {
        const int hs = e / 48;
        h = (hs < 2) ? hs : 188 + hs;         // 0,1,190,191
        w4 = e % 48;
    } else {
        const int e2 = e - 192;
        h = 2 + (e2 >> 1);
        w4 = (e2 & 1) ? 47 : 0;
    }
    motif_quad<true>(x, pf, pi, out, b, ch, h, w4 * 4);
}

// ---------------------------------------------------------------------------
extern "C" void kernel_launch(void* const* d_in, const int* in_sizes, int n_in,
                              void* d_out, int out_size, void* d_ws, size_t ws_size,
                              hipStream_t stream)
{
    const float* x = (const float*)d_in[0];
    float* out = (float*)d_out;

    double* gram = (double*)d_ws;
    const size_t gram_bytes = (size_t)32 * PP * PP * sizeof(double); // 5,308,416 B
    float* pf = (float*)((char*)d_ws + gram_bytes);
    int* pi = (int*)((char*)d_ws + gram_bytes + 256);

    gram_kernel<<<2304, 192, 0, stream>>>(x, gram);
    topk_kernel<<<16, 320, 0, stream>>>(gram, pf, pi);
    out_interior<<<17296, 256, 0, stream>>>(x, pf, pi, out);  // 2*256*188*46/256
    out_edge<<<1136, 256, 0, stream>>>(x, pf, pi, out);       // 2*256*568/256
}

// Round 9
// 405.256 us; speedup vs baseline: 1.3550x; 1.0556x over previous
//
#include <hip/hip_runtime.h>
#include <math.h>

// Problem constants
#define NB 2
#define NC 256
#define CG 16
#define HH 192
#define WW 192
#define HO 190
#define PP 144

typedef float v2f __attribute__((ext_vector_type(2)));

// LDS: 7348 floats = 29392 B -> 5 blocks/CU (with VGPR<=128: 15 waves/CU).
// Band area: 35 rows x 196 (row r at r*196: [0..3]=pads always zero,
//   [4..195]=data). Window reads at r*196 + 2+v+dj: left spill -> own pads
//   [2,3], right spill -> next row's pads [0,1] (never written by staging).
// Epilogue: edge rows 0..11 (same layout), row 12 = permanent zero guard
//   (slots [0,1] catch edge-row-11 right spill), red[192][25] at 2548.
#define SMEM_FLOATS 7348

// ---------------------------------------------------------------------------
// Kernel 1: correlation-decomposed Gram. Same per-accumulator FMA values and
// order as rounds 1-8 -> bit-identical gram.
// THIS ROUND: cut VALU ISSUE COUNT (busy-time was invariant ~110us across
// r2/6/8 = 2x the 53us FMA floor):
//  (a) packed f32: mid2[25] as float2 {chanA,chanB}; __builtin_elementwise_fma
//      -> v_pk_fma_f32: 50 -> 25 FMA instrs/step (per-component IEEE fma,
//      same order -> bit-identical).
//  (b) strength-reduced addressing: LDS via running index (+=196/step, dj*4
//      immediates); global refills via per-group pointer bump (+6*WW) with
//      P*WW immediate offsets (<=3840 fits 13-bit signed).
// Structure otherwise = round-8 winner: 192 thr, (192,2), 6-phase pipelined
// window ring, 35-row chained bands, XCD-clustered swizzle.
// ---------------------------------------------------------------------------
__global__ __launch_bounds__(192, 2) void gram_kernel(const float* __restrict__ x,
                                                      double* __restrict__ gram)
{
    __shared__ float smem[SMEM_FLOATS];
    float* const red_s = smem + 2548;

    const int v = threadIdx.x;                // column 0..191

    // XCD-clustered decode: bid%8 = intended XCD; half-group hg (36 blocks)
    // pinned to XCD hg%8. Bijective over 2304 blocks.
    const int bid = blockIdx.x;
    const int vx = bid & 7;
    const int tq = bid >> 3;                  // 0..287
    const int idxw = tq / 36;                 // 0..7
    const int rr0 = tq - idxw * 36;           // 0..35
    const int hg = idxw * 8 + vx;             // 0..63
    const int bg = hg >> 1;
    int r = rr0 + 36 * (hg & 1);              // 0..71
    int c2 = 0;
    while (r >= (c2 + 2) / 2) { r -= (c2 + 2) / 2; ++c2; }
    const int c1a = 2 * r;
    int c1b = 2 * r + 1;
    const bool bval = (c1b <= c2);
    if (!bval) c1b = c2;
    const int b = bg >> 4, g = bg & 15;

    const float* __restrict__ xa  = x + ((size_t)(b * NC + g * CG + c1a)) * (HH * WW);
    const float* __restrict__ xb  = x + ((size_t)(b * NC + g * CG + c1b)) * (HH * WW);
    const float* __restrict__ x2g = x + ((size_t)(b * NC + g * CG + c2 )) * (HH * WW);

    // zero pad slots [0..3] of rows 0..36 once; staging never writes pads.
    if (v < 148) smem[(v >> 2) * 196 + (v & 3)] = 0.f;

    v2f mid2[25];                             // .x = chan c1a, .y = chan c1b
#pragma unroll
    for (int o = 0; o < 25; ++o) mid2[o] = (v2f){0.f, 0.f};

    float win[6][5];                          // slot s holds local row L, L%6==s
    v2f cab[6];                               // cab[(u-2)%6] = {xa,xb} row u
#pragma unroll
    for (int k = 0; k < 6; ++k)               // rows 2..7
        cab[k] = (v2f){xa[(size_t)(2 + k) * WW + v], xb[(size_t)(2 + k) * WW + v]};

    // strength-reduced global refill pointers: point at row (ubase+6), col v
    const float* pa = xa + (size_t)8 * WW + v;   // first group has ubase=2
    const float* pb = xb + (size_t)8 * WW + v;
    int lds_off;                              // float idx of WPF row start

// One u-step. P = phase = LS%6 (compile-time). Consumes cab[P] (row u) and
// win slots (P+kk)%6 (local rows LS..LS+4, loaded >=1 step earlier).
//   WPF: window row local LS+5 -> slot (P+5)%6 via running lds_off;
//   GPF: cab[P] <- rows at pa/pb[P*WW] (row ubase+6+P, consumed 6 steps on).
#define USTEP6(P, WPF, GPF)                                                   \
    {                                                                         \
        const v2f ab = cab[(P)];                                              \
        if (GPF) cab[(P)] = (v2f){pa[(P) * WW], pb[(P) * WW]};                \
        if (WPF) {                                                            \
            const float* wr = &smem[lds_off];                                 \
            _Pragma("unroll")                                                 \
            for (int dj = 0; dj < 5; ++dj)                                    \
                win[((P) + 5) % 6][dj] = wr[dj];                              \
        }                                                                     \
        lds_off += 196;                                                       \
        _Pragma("unroll")                                                     \
        for (int kk = 0; kk < 5; ++kk) {                                      \
            _Pragma("unroll")                                                 \
            for (int dj = 0; dj < 5; ++dj) {                                  \
                const float xv = win[((P) + kk) % 6][dj];                     \
                mid2[kk * 5 + dj] = __builtin_elementwise_fma(                \
                    ab, (v2f){xv, xv}, mid2[kk * 5 + dj]);                    \
            }                                                                 \
        }                                                                     \
    }

    // 7 bands: 6 x 30 steps (u=2..181, stage 35 rows: local 0..34) + tail
    // 8 steps (u=182..189, stage 12 rows: local 0..11 = abs 180..191).
    // Step LS prefetches window row local LS+5; LS=29 loads local 34 which
    // IS next band's local 4 (same abs row) -> no prologue after band 0.
    for (int band = 0; band < 7; ++band) {
        const bool full = (band < 6);
        const int u0 = 2 + band * 30;
        const int row0 = u0 - 2;
        const int limit = (full ? 35 : 12) * 48;   // float4 slots
        __syncthreads();
        for (int it = 0; it < (full ? 9 : 3); ++it) {
            const int idx = it * 192 + v;
            if (idx < limit) {
                const int rr2 = idx / 48;
                const int c4 = (idx - rr2 * 48) * 4;
                const float4 val = *(const float4*)(x2g + (size_t)(row0 + rr2) * WW + c4);
                *(float4*)(&smem[rr2 * 196 + 4 + c4]) = val;
            }
        }
        __syncthreads();
        if (band == 0) {
            // only prologue of the whole kernel: locals 0..4 -> slots 0..4
#pragma unroll
            for (int k = 0; k < 5; ++k)
#pragma unroll
            for (int dj = 0; dj < 5; ++dj)
                win[k][dj] = smem[k * 196 + 2 + v + dj];
        }
        lds_off = 5 * 196 + 2 + v;            // local row 5, this band

        if (full) {
            for (int it = 0; it < 5; ++it) {  // rolled: small hot body
                USTEP6(0, 1, 1) USTEP6(1, 1, 1) USTEP6(2, 1, 1)
                USTEP6(3, 1, 1) USTEP6(4, 1, 1) USTEP6(5, 1, 1)
                pa += 6 * WW; pb += 6 * WW;   // next group's refill base
            }
        } else {
            // steps 0..5 (u=182..187); GPF only P<=1 (rows 188,189)
            USTEP6(0, 1, 1) USTEP6(1, 1, 1) USTEP6(2, 1, 0)
            USTEP6(3, 1, 0) USTEP6(4, 1, 0) USTEP6(5, 1, 0)
            // steps 6,7 (u=188,189): phases 0,1; WPF for LS=6 (local 11)
            USTEP6(0, 1, 0) USTEP6(1, 0, 0)
        }
    }
#undef USTEP6

    // stage edge buffer: buf i<6 -> abs row i-2 (OOB zero), i>=6 -> 188+(i-6).
    // Row 12 = zero guard (pads catch edge-row-11 right spill); red_s at 2548.
    __syncthreads();
    for (int i = 0; i < 12; ++i) {
        const int ar = (i < 6) ? (i - 2) : (188 + i - 6);
        const float val = (ar >= 0 && ar <= 191) ? x2g[(size_t)ar * WW + v] : 0.f;
        smem[i * 196 + 4 + v] = val;
    }
    __syncthreads();

    double* const gp = gram + (size_t)bg * (PP * PP);

#pragma unroll
    for (int i1 = 0; i1 < 3; ++i1) {
        const int ra = (i1 == 0) ? 0 : ((i1 == 1) ? 1 : 190);
        const int rb = (i1 == 0) ? 1 : ((i1 == 1) ? 190 : 191);
#pragma unroll
        for (int c = 0; c < 2; ++c) {
            const float* __restrict__ xc = (c == 0) ? xa : xb;
            const float xra = xc[(size_t)ra * WW + v];
            const float xrb = xc[(size_t)rb * WW + v];
#pragma unroll
            for (int k = 0; k < 5; ++k) {
                const int bufa = (ra < 2) ? (ra + k) : (ra + k - 184);
                const int bufb = (rb < 2) ? (rb + k) : (rb + k - 184);
#pragma unroll
                for (int dj = 0; dj < 5; ++dj) {
                    const int q = k * 5 + dj;
                    float cw = (c == 0) ? mid2[q].x : mid2[q].y;
                    cw = fmaf(xra, smem[bufa * 196 + 2 + v + dj], cw);
                    cw = fmaf(xrb, smem[bufb * 196 + 2 + v + dj], cw);
                    red_s[v * 25 + q] = cw;
                }
            }
            __syncthreads();
            float e0 = 0.f, e1 = 0.f, e190 = 0.f, e191 = 0.f;
            if (v < 25) {
                e0   = red_s[0 * 25 + v];
                e1   = red_s[1 * 25 + v];
                e190 = red_s[190 * 25 + v];
                e191 = red_s[191 * 25 + v];
            }
            __syncthreads();
            // tree reduce over columns: 192 -> 96 -> ... -> 3 (stride 25: conflict-free)
#pragma unroll
            for (int s = 96; s >= 3; s >>= 1) {
                for (int idx = v; idx < s * 25; idx += 192) {
                    const int vv = idx / 25, o = idx - vv * 25;
                    red_s[vv * 25 + o] += red_s[(vv + s) * 25 + o];
                }
                __syncthreads();
            }
            if (v < 25 && (c == 0 || bval)) {
                const int di = v / 5 - 2, dj = v - (v / 5) * 5 - 2;
                const int i2 = i1 + di;
                if (i2 >= 0 && i2 <= 2) {
                    const float S = red_s[0 * 25 + v] + red_s[1 * 25 + v] + red_s[2 * 25 + v];
                    const int c1 = (c == 0) ? c1a : c1b;
#pragma unroll
                    for (int j1 = 0; j1 < 3; ++j1) {
                        const int j2 = j1 + dj;
                        if (j2 < 0 || j2 > 2) continue;
                        const float W = S - ((j1 == 0) ? (e190 + e191)
                                          : (j1 == 1) ? (e0 + e191)
                                                      : (e0 + e1));
                        const int p = c1 * 9 + i1 * 3 + j1;
                        const int q = c2 * 9 + i2 * 3 + j2;
                        gp[p * PP + q] = (double)W;
                        if (c1 != c2) gp[q * PP + p] = (double)W;
                    }
                }
            }
            __syncthreads();   // red reused by next (i1,c)
        }
    }
}

// ---------------------------------------------------------------------------
// Kernel 2: per-group argmin (f64 d2, first-min tiebreak), bincount over both
// batches, stable top-3 (smallest index on count ties, matching lax.top_k).
// ---------------------------------------------------------------------------
__global__ __launch_bounds__(320) void topk_kernel(const double* __restrict__ gram,
                                                   float* __restrict__ pf,
                                                   int* __restrict__ pi)
{
    const int g = blockIdx.x;
    __shared__ double sdiag[2][PP];
    __shared__ int counts[PP];
    const int tid = threadIdx.x;
    if (tid < PP) counts[tid] = 0;
    if (tid < 2 * PP) {
        const int b = tid / PP, p = tid % PP;
        const double* gb = gram + (size_t)(b * 16 + g) * (PP * PP);
        sdiag[b][p] = gb[p * PP + p];
    }
    __syncthreads();
    if (tid < 2 * PP) {
        const int b = tid / PP, p = tid % PP;
        const double* row = gram + ((size_t)(b * 16 + g) * PP + p) * PP;
        const double sp = sdiag[b][p];
        double best = 1e300;
        int bi = 0;
        for (int q = 0; q < PP; ++q) {
            if (q == p) continue;
            const double d2 = sp + sdiag[b][q] - 2.0 * row[q];
            if (d2 < best) { best = d2; bi = q; }   // strict < : first occurrence
        }
        atomicAdd(&counts[bi], 1);
    }
    __syncthreads();
    if (tid == 0) {
        int sel[3], cv[3];
        for (int o = 0; o < 3; ++o) {
            int bc = -1, bp = 0;
            for (int p = 0; p < PP; ++p) {
                bool taken = false;
                for (int u = 0; u < o; ++u) if (sel[u] == p) taken = true;
                if (!taken && counts[p] > bc) { bc = counts[p]; bp = p; } // > keeps lowest idx
            }
            sel[o] = bp; cv[o] = bc;
        }
        const int tot = cv[0] + cv[1] + cv[2];
        for (int o = 0; o < 3; ++o) {
            pf[g * 4 + o] = (float)cv[o];
            pi[g * 4 + o] = sel[o];
        }
        pf[g * 4 + 3] = (float)tot;
    }
}

// ---------------------------------------------------------------------------
// Kernel 3: fused scale->floor->fold stencil. t1,t2 are plain f32 muls
// (== __fmul_rn == reference). Division via f64 reciprocal-multiply:
// bit-exact (total<=288 => exact quotients >=2^-34 rel from any f32 rounding
// midpoint, exact ties impossible, f64 error <=2^-52 -> identical rounding).
// Interior and edge in separate kernels (no divergent waves).
// ---------------------------------------------------------------------------
template <bool EDGE>
__device__ __forceinline__ void motif_quad(const float* __restrict__ x,
                                           const float* __restrict__ pf,
                                           const int* __restrict__ pi,
                                           float* __restrict__ out,
                                           int b, int ch, int h, int w0)
{
    const int g = ch >> 4;
    const size_t base = ((size_t)(b * NC + ch)) * (HH * WW);
    const float4 xv4 = *(const float4*)(x + base + (size_t)h * WW + w0);
    const float xs[4] = {xv4.x, xv4.y, xv4.z, xv4.w};
    float acc[4] = {0.f, 0.f, 0.f, 0.f};
    const float total = pf[g * 4 + 3];
    const double invd = 1.0 / (double)total;

#pragma unroll
    for (int o = 0; o < 3; ++o) {
        const int p = pi[g * 4 + o];
        const float cff = pf[g * 4 + o];
        const int co = p / 9;
        const int kk = p - co * 9;
        const int io = kk / 3, jo = kk - (kk / 3) * 3;
        const float* Rb = x + ((size_t)(b * NC + g * CG + co)) * (HH * WW);
#pragma unroll
        for (int i = 0; i < 3; ++i) {
            const int ho = h - i;
            bool rowok = true;
            int hr = ho + io;
            if (EDGE) {
                rowok = (ho >= 0) && (ho < HO);
                hr = hr < 0 ? 0 : (hr > HH - 1 ? HH - 1 : hr);
            }
            const float* row = Rb + (size_t)hr * WW;
            float rv[6];
#pragma unroll
            for (int u = 0; u < 6; ++u) {
                int col = w0 - 2 + jo + u;
                if (EDGE) col = col < 0 ? 0 : (col > WW - 1 ? WW - 1 : col);
                rv[u] = row[col];
            }
#pragma unroll
            for (int j = 0; j < 3; ++j)
#pragma unroll
            for (int q = 0; q < 4; ++q) {
                const float r2 = rv[q - j + 2];
                const float t1 = xs[q] * r2;                  // == __fmul_rn
                const float t2 = t1 * cff;                    // == __fmul_rn
                const float qf = (float)((double)t2 * invd);  // == __fdiv_rn(t2,total)
                const float vfl = floorf(qf);
                if (EDGE) {
                    const int wo = w0 + q - j;
                    const bool ok = rowok && (wo >= 0) && (wo < HO);
                    acc[q] += ok ? vfl : 0.f;
                } else {
                    acc[q] += vfl;
                }
            }
        }
    }
    float4 ov = make_float4(acc[0], acc[1], acc[2], acc[3]);
    *(float4*)(out + base + (size_t)h * WW + w0) = ov;
}

// interior: h in [2,189], w4 in [1,46] -> no clamps/masks anywhere.
__global__ __launch_bounds__(256) void out_interior(const float* __restrict__ x,
                                                    const float* __restrict__ pf,
                                                    const int* __restrict__ pi,
                                                    float* __restrict__ out)
{
    const int gid = blockIdx.x * 256 + threadIdx.x;
    const int w4i = gid % 46;
    int t = gid / 46;
    const int h = 2 + t % 188; t /= 188;
    const int ch = t & 255;
    const int b = t >> 8;
    motif_quad<false>(x, pf, pi, out, b, ch, h, (w4i + 1) * 4);
}

// edge: 568 quads per (b,ch): h in {0,1,190,191} x all 48 w4, plus
// h in [2,189] x w4 in {0,47}.
__global__ __launch_bounds__(256) void out_edge(const float* __restrict__ x,
                                                const float* __restrict__ pf,
                                                const int* __restrict__ pi,
                                                float* __restrict__ out)
{
    const int gid = blockIdx.x * 256 + threadIdx.x;
    const int e = gid % 568;
    int t = gid / 568;
    const int ch = t & 255;
    const int b = t >> 8;
    int h, w4;
    if (e < 192) {
        const int hs = e / 48;
        h = (hs < 2) ? hs : 188 + hs;         // 0,1,190,191
        w4 = e % 48;
    } else {
        const int e2 = e - 192;
        h = 2 + (e2 >> 1);
        w4 = (e2 & 1) ? 47 : 0;
    }
    motif_quad<true>(x, pf, pi, out, b, ch, h, w4 * 4);
}

// ---------------------------------------------------------------------------
extern "C" void kernel_launch(void* const* d_in, const int* in_sizes, int n_in,
                              void* d_out, int out_size, void* d_ws, size_t ws_size,
                              hipStream_t stream)
{
    const float* x = (const float*)d_in[0];
    float* out = (float*)d_out;

    double* gram = (double*)d_ws;
    const size_t gram_bytes = (size_t)32 * PP * PP * sizeof(double); // 5,308,416 B
    float* pf = (float*)((char*)d_ws + gram_bytes);
    int* pi = (int*)((char*)d_ws + gram_bytes + 256);

    gram_kernel<<<2304, 192, 0, stream>>>(x, gram);
    topk_kernel<<<16, 320, 0, stream>>>(gram, pf, pi);
    out_interior<<<17296, 256, 0, stream>>>(x, pf, pi, out);  // 2*256*188*46/256
    out_edge<<<1136, 256, 0, stream>>>(x, pf, pi, out);       // 2*256*568/256
}